// Round 5
// baseline (493.095 us; speedup 1.0000x reference)
//
#include <hip/hip_runtime.h>

// PWC-Net correlation (md=4, 81 disps) + leaky_relu(0.1), mean over C=256.
// B=8 C=256 H=96 W=128, f32 in/out.
//
// Block = 9 waves (576 thr), one wave per dy. Tile = 2 rows x 128 w.
// Lane owns 4 consecutive w pixels x 9 dx = 36 f32 accumulators.
// Channels in chunks of 8, f16-pair packed in LDS, v_dot2_f32_f16.
// R5: DOUBLE-BUFFERED LDS, one barrier per chunk (was 2), global prefetch
// issued at end of section, consumed after next COMPUTE (T14 issue-early/
// write-late). R4 lesson: vmcnt-wait between two barriers = lockstep stall,
// 60% of wall clock. R2 lesson: never cap VGPR via launch_bounds min-waves.
// Register budget target <=102 VGPR so 2 blocks (18 waves) fit per CU.

#define B_ 8
#define C_ 256
#define H_ 96
#define W_ 128
#define TH 2
#define NROW2 (TH + 8)           // 10 x2 rows staged
#define CC 8
#define NCH (C_ / CC)            // 32 chunks
#define HW (H_ * W_)
#define CHSTRIDE (CC * HW)       // floats, fits u32
#define S1SZ (TH * 512)          // 1024 u32 per buffer
#define S2SZ (NROW2 * 544)       // 5440 u32 per buffer
#define NX2TASK (NROW2 * 34 * 4) // 1360

typedef __fp16 h2_t __attribute__((ext_vector_type(2)));
union H2U { unsigned int u; h2_t h; };

__device__ __forceinline__ h2_t u_as_h2(unsigned int u) { H2U x; x.u = u; return x.h; }

__device__ __forceinline__ unsigned int packh2(float a, float b) {
    H2U x; x.h = __builtin_amdgcn_cvt_pkrtz(a, b); return x.u;
}

#if __has_builtin(__builtin_amdgcn_fdot2)
__device__ __forceinline__ float dot2(unsigned int a, unsigned int b, float c) {
    return __builtin_amdgcn_fdot2(u_as_h2(a), u_as_h2(b), c, false);
}
#else
__device__ __forceinline__ float dot2(unsigned int a, unsigned int b, float c) {
    h2_t ha = u_as_h2(a), hb = u_as_h2(b);
    return c + (float)ha[0] * (float)hb[0] + (float)ha[1] * (float)hb[1];
}
#endif

__global__ __launch_bounds__(576)
void corr_kernel(const float* __restrict__ x1, const float* __restrict__ x2,
                 float* __restrict__ out)
{
    __shared__ __align__(16) unsigned int s1[2][S1SZ];   // 8 KB
    __shared__ __align__(16) unsigned int s2[2][S2SZ];   // 42.5 KB

    const int bid = blockIdx.x;
    const int b   = bid & 7;          // XCD == batch (round-robin dispatch)
    const int h0  = (bid >> 3) * TH;
    const int tid = threadIdx.x;
    const int dy  = tid >> 6;         // wave id = dy (0..8)
    const int lane = tid & 63;
    const int hr  = lane >> 5;        // 0..1
    const int wq  = lane & 31;        // 32 groups of 4 w pixels

    // ---------------- staging task setup (u32 offsets off SGPR base) -------
    // x1: tid<256. task u=tid: cp=u&3, w4=(u>>2)&31, r=u>>7.
    // LDS u32 idx for pixel w, ch-pair cp, row r:
    //   r*512 + (w>>3)*32 + (((w&7)^((w>>3)&7)^r)<<2) + cp
    const bool x1act = (tid < 256);
    const int cpx = tid & 3;
    const int w4  = (tid >> 2) & 31;
    const int rx  = (tid >> 7) & 1;
    const unsigned a0off =
        ((unsigned)(b * C_ + 2 * cpx) * H_ + (unsigned)(h0 + rx)) * W_ + w4 * 4;
    const int c1 = rx * 512 + (w4 >> 1) * 32 + cpx;
    const int X1 = (4 * (w4 & 1)) ^ ((w4 >> 1) & 7) ^ rx;

    // x2: 1360 tasks (10 rows x 34 float4-groups x 4 cp)
    unsigned b0off[3];
    int  c2[3], X2[3];
    bool xv[3];
    #pragma unroll
    for (int i = 0; i < 3; ++i) {
        int v = (i == 0) ? (tid - 256) : ((i == 1) ? (tid + 320) : (tid + 896));
        bool act = (i == 0) ? (tid >= 256) : (v < NX2TASK);
        if (!act) v = 260;                 // any valid dummy
        const int cp = v & 3;
        const int rest = v >> 2;
        const int g = rest % 34;           // float4 group in padded width (136)
        const int r = rest / 34;           // staged row 0..9
        const int hh = h0 + r - 4;
        const bool val = act && (hh >= 0) && (hh < H_) && (g >= 1) && (g <= 32);
        xv[i] = val;
        const int hhc = val ? hh : 0;
        const int gc  = val ? g : 1;
        b0off[i] = ((unsigned)(b * C_ + 2 * cp) * H_ + (unsigned)hhc) * W_
                 + (unsigned)(gc * 4 - 4);
        c2[i] = r * 544 + (g >> 1) * 32 + cp;
        X2[i] = (4 * (g & 1)) ^ ((g >> 1) & 7) ^ (r & 7);
    }

    float4 pr0a, pr0b, pr1a, pr1b, pr2a, pr2b;

    auto LOAD = [&](int cc) {
        const unsigned co = (unsigned)cc * (unsigned)CHSTRIDE;
        if (x1act) {
            pr0a = *reinterpret_cast<const float4*>(x1 + a0off + co);
            pr0b = *reinterpret_cast<const float4*>(x1 + a0off + co + HW);
        } else if (xv[0]) {
            pr0a = *reinterpret_cast<const float4*>(x2 + b0off[0] + co);
            pr0b = *reinterpret_cast<const float4*>(x2 + b0off[0] + co + HW);
        }
        if (xv[1]) {
            pr1a = *reinterpret_cast<const float4*>(x2 + b0off[1] + co);
            pr1b = *reinterpret_cast<const float4*>(x2 + b0off[1] + co + HW);
        }
        if (xv[2]) {
            pr2a = *reinterpret_cast<const float4*>(x2 + b0off[2] + co);
            pr2b = *reinterpret_cast<const float4*>(x2 + b0off[2] + co + HW);
        }
    };
    auto WRITE = [&](int sel) {            // called with literal sel -> folds
        unsigned int* S1 = s1[sel];
        unsigned int* S2 = s2[sel];
        if (x1act) {
            S1[c1 + ((0 ^ X1) << 2)] = packh2(pr0a.x, pr0b.x);
            S1[c1 + ((1 ^ X1) << 2)] = packh2(pr0a.y, pr0b.y);
            S1[c1 + ((2 ^ X1) << 2)] = packh2(pr0a.z, pr0b.z);
            S1[c1 + ((3 ^ X1) << 2)] = packh2(pr0a.w, pr0b.w);
        } else if (xv[0]) {
            S2[c2[0] + ((0 ^ X2[0]) << 2)] = packh2(pr0a.x, pr0b.x);
            S2[c2[0] + ((1 ^ X2[0]) << 2)] = packh2(pr0a.y, pr0b.y);
            S2[c2[0] + ((2 ^ X2[0]) << 2)] = packh2(pr0a.z, pr0b.z);
            S2[c2[0] + ((3 ^ X2[0]) << 2)] = packh2(pr0a.w, pr0b.w);
        }
        if (xv[1]) {
            S2[c2[1] + ((0 ^ X2[1]) << 2)] = packh2(pr1a.x, pr1b.x);
            S2[c2[1] + ((1 ^ X2[1]) << 2)] = packh2(pr1a.y, pr1b.y);
            S2[c2[1] + ((2 ^ X2[1]) << 2)] = packh2(pr1a.z, pr1b.z);
            S2[c2[1] + ((3 ^ X2[1]) << 2)] = packh2(pr1a.w, pr1b.w);
        }
        if (xv[2]) {
            S2[c2[2] + ((0 ^ X2[2]) << 2)] = packh2(pr2a.x, pr2b.x);
            S2[c2[2] + ((1 ^ X2[2]) << 2)] = packh2(pr2a.y, pr2b.y);
            S2[c2[2] + ((2 ^ X2[2]) << 2)] = packh2(pr2a.z, pr2b.z);
            S2[c2[2] + ((3 ^ X2[2]) << 2)] = packh2(pr2a.w, pr2b.w);
        }
    };

    // ---------------- compute setup ----------------
    const int base1 = hr * 512 + (wq >> 1) * 32;
    const int S1X   = (4 * (wq & 1)) ^ ((wq >> 1) & 7) ^ hr;
    const int row   = hr + dy;            // 0..9
    const int row7  = row & 7;

    int a2[12];                           // chunk-invariant x2 read addresses
    #pragma unroll
    for (int t = 0; t < 12; ++t) {
        const int sp = 4 * wq + t;        // padded pixel index 0..135
        a2[t] = row * 544 + (sp >> 3) * 32
              + (((sp & 7) ^ ((sp >> 3) & 7) ^ row7) << 2);
    }

    float acc[4][9];
    #pragma unroll
    for (int p = 0; p < 4; ++p)
        #pragma unroll
        for (int d = 0; d < 9; ++d) acc[p][d] = 0.f;

    auto COMPUTE = [&](int sel) {         // called with literal sel -> folds
        const unsigned int* S1 = s1[sel];
        const unsigned int* S2 = s2[sel];
        uint4 x1v[4];
        #pragma unroll
        for (int p = 0; p < 4; ++p)
            x1v[p] = *reinterpret_cast<const uint4*>(&S1[base1 + ((p ^ S1X) << 2)]);
        #pragma unroll
        for (int t = 0; t < 12; ++t) {
            const uint4 x2v = *reinterpret_cast<const uint4*>(&S2[a2[t]]);
            #pragma unroll
            for (int p = 0; p < 4; ++p) {
                const int dxx = t - p;          // compile-time after unroll
                if (dxx >= 0 && dxx <= 8) {
                    float a = acc[p][dxx];
                    a = dot2(x1v[p].x, x2v.x, a);
                    a = dot2(x1v[p].y, x2v.y, a);
                    a = dot2(x1v[p].z, x2v.z, a);
                    a = dot2(x1v[p].w, x2v.w, a);
                    acc[p][dxx] = a;
                }
            }
        }
    };

    // ---------------- pipelined chunk loop (dbuf, 1 barrier/chunk) ---------
    // zero pad slots of both s2 buffers (never rewritten)
    for (int i = tid; i < 2 * S2SZ; i += 576) (&s2[0][0])[i] = 0u;
    LOAD(0);
    __syncthreads();                  // zeros visible before any WRITE
    WRITE(0);
    LOAD(1);
    __syncthreads();                  // buf0 ready

    #pragma unroll 1
    for (int cc = 0; cc < NCH; cc += 2) {
        COMPUTE(0);                   // chunk cc
        WRITE(1);                     // chunk cc+1 (loaded last section)
        if (cc + 2 < NCH) LOAD(cc + 2);
        __syncthreads();
        COMPUTE(1);                   // chunk cc+1
        if (cc + 2 < NCH) {
            WRITE(0);                 // chunk cc+2
            if (cc + 3 < NCH) LOAD(cc + 3);
        }
        __syncthreads();
    }

    // ---------------- epilogue: mean + leaky_relu + coalesced f32x4 writes -
    const float inv = 1.0f / 256.0f;
    float* ob = out + (((size_t)(b * 81 + dy * 9)) * H_ + (h0 + hr)) * W_ + wq * 4;
    #pragma unroll
    for (int dxx = 0; dxx < 9; ++dxx) {
        float4 o;
        float v;
        v = acc[0][dxx] * inv; o.x = v >= 0.f ? v : 0.1f * v;
        v = acc[1][dxx] * inv; o.y = v >= 0.f ? v : 0.1f * v;
        v = acc[2][dxx] * inv; o.z = v >= 0.f ? v : 0.1f * v;
        v = acc[3][dxx] * inv; o.w = v >= 0.f ? v : 0.1f * v;
        *reinterpret_cast<float4*>(ob + (size_t)dxx * HW) = o;
    }
}

extern "C" void kernel_launch(void* const* d_in, const int* in_sizes, int n_in,
                              void* d_out, int out_size, void* d_ws, size_t ws_size,
                              hipStream_t stream) {
    const float* x1 = (const float*)d_in[0];
    const float* x2 = (const float*)d_in[1];
    float* out = (float*)d_out;
    corr_kernel<<<dim3(B_ * (H_ / TH)), dim3(576), 0, stream>>>(x1, x2, out);
}

// Round 6
// 489.493 us; speedup vs baseline: 1.0074x; 1.0074x over previous
//
#include <hip/hip_runtime.h>

// PWC-Net correlation (md=4, 81 disps) + leaky_relu(0.1), mean over C=256.
// B=8 C=256 H=96 W=128, f32 in/out.
//
// Block = 9 waves (576 thr), one wave per dy. Tile = 2 rows x 128 w.
// Lane owns 4 consecutive w pixels x 9 dx = 36 f32 accumulators.
// Channels in chunks of 8, f16-pair packed in LDS, v_dot2_f32_f16.
// Double-buffered LDS, one barrier per chunk, prefetch issued a chunk
// ahead (T14 issue-early / write-late).
// R5 lesson: compiler's occupancy heuristic pins VGPR=84 (6 waves/SIMD)
// and SPILLS the pipeline state (533MB scratch writes) -- launch_bounds
// does NOT override it. Fix: amdgpu_waves_per_eu(2,4) gives the
// allocator a 2-waves/EU budget (256 VGPR cap) and forbids the
// heuristic from targeting >4 waves/EU.

#define B_ 8
#define C_ 256
#define H_ 96
#define W_ 128
#define TH 2
#define NROW2 (TH + 8)           // 10 x2 rows staged
#define CC 8
#define NCH (C_ / CC)            // 32 chunks
#define HW (H_ * W_)
#define CHSTRIDE (CC * HW)       // floats, fits u32
#define S1SZ (TH * 512)          // 1024 u32 per buffer
#define S2SZ (NROW2 * 544)       // 5440 u32 per buffer
#define NX2TASK (NROW2 * 34 * 4) // 1360

typedef __fp16 h2_t __attribute__((ext_vector_type(2)));
union H2U { unsigned int u; h2_t h; };

__device__ __forceinline__ h2_t u_as_h2(unsigned int u) { H2U x; x.u = u; return x.h; }

__device__ __forceinline__ unsigned int packh2(float a, float b) {
    H2U x; x.h = __builtin_amdgcn_cvt_pkrtz(a, b); return x.u;
}

#if __has_builtin(__builtin_amdgcn_fdot2)
__device__ __forceinline__ float dot2(unsigned int a, unsigned int b, float c) {
    return __builtin_amdgcn_fdot2(u_as_h2(a), u_as_h2(b), c, false);
}
#else
__device__ __forceinline__ float dot2(unsigned int a, unsigned int b, float c) {
    h2_t ha = u_as_h2(a), hb = u_as_h2(b);
    return c + (float)ha[0] * (float)hb[0] + (float)ha[1] * (float)hb[1];
}
#endif

__global__ __launch_bounds__(576)
__attribute__((amdgpu_waves_per_eu(2, 4)))
void corr_kernel(const float* __restrict__ x1, const float* __restrict__ x2,
                 float* __restrict__ out)
{
    __shared__ __align__(16) unsigned int s1[2][S1SZ];   // 8 KB
    __shared__ __align__(16) unsigned int s2[2][S2SZ];   // 42.5 KB

    const int bid = blockIdx.x;
    const int b   = bid & 7;          // XCD == batch (round-robin dispatch)
    const int h0  = (bid >> 3) * TH;
    const int tid = threadIdx.x;
    const int dy  = tid >> 6;         // wave id = dy (0..8)
    const int lane = tid & 63;
    const int hr  = lane >> 5;        // 0..1
    const int wq  = lane & 31;        // 32 groups of 4 w pixels

    // ---------------- staging task setup (u32 offsets off SGPR base) -------
    // x1: tid<256. task u=tid: cp=u&3, w4=(u>>2)&31, r=u>>7.
    // LDS u32 idx for pixel w, ch-pair cp, row r:
    //   r*512 + (w>>3)*32 + (((w&7)^((w>>3)&7)^r)<<2) + cp
    const bool x1act = (tid < 256);
    const int cpx = tid & 3;
    const int w4  = (tid >> 2) & 31;
    const int rx  = (tid >> 7) & 1;
    const unsigned a0off =
        ((unsigned)(b * C_ + 2 * cpx) * H_ + (unsigned)(h0 + rx)) * W_ + w4 * 4;
    const int c1 = rx * 512 + (w4 >> 1) * 32 + cpx;
    const int X1 = (4 * (w4 & 1)) ^ ((w4 >> 1) & 7) ^ rx;

    // x2: 1360 tasks (10 rows x 34 float4-groups x 4 cp)
    unsigned b0off[3];
    int  c2[3], X2[3];
    bool xv[3];
    #pragma unroll
    for (int i = 0; i < 3; ++i) {
        int v = (i == 0) ? (tid - 256) : ((i == 1) ? (tid + 320) : (tid + 896));
        bool act = (i == 0) ? (tid >= 256) : (v < NX2TASK);
        if (!act) v = 260;                 // any valid dummy
        const int cp = v & 3;
        const int rest = v >> 2;
        const int g = rest % 34;           // float4 group in padded width (136)
        const int r = rest / 34;           // staged row 0..9
        const int hh = h0 + r - 4;
        const bool val = act && (hh >= 0) && (hh < H_) && (g >= 1) && (g <= 32);
        xv[i] = val;
        const int hhc = val ? hh : 0;
        const int gc  = val ? g : 1;
        b0off[i] = ((unsigned)(b * C_ + 2 * cp) * H_ + (unsigned)hhc) * W_
                 + (unsigned)(gc * 4 - 4);
        c2[i] = r * 544 + (g >> 1) * 32 + cp;
        X2[i] = (4 * (g & 1)) ^ ((g >> 1) & 7) ^ (r & 7);
    }

    float4 pr0a, pr0b, pr1a, pr1b, pr2a, pr2b;

    auto LOAD = [&](int cc) {
        const unsigned co = (unsigned)cc * (unsigned)CHSTRIDE;
        if (x1act) {
            pr0a = *reinterpret_cast<const float4*>(x1 + a0off + co);
            pr0b = *reinterpret_cast<const float4*>(x1 + a0off + co + HW);
        } else if (xv[0]) {
            pr0a = *reinterpret_cast<const float4*>(x2 + b0off[0] + co);
            pr0b = *reinterpret_cast<const float4*>(x2 + b0off[0] + co + HW);
        }
        if (xv[1]) {
            pr1a = *reinterpret_cast<const float4*>(x2 + b0off[1] + co);
            pr1b = *reinterpret_cast<const float4*>(x2 + b0off[1] + co + HW);
        }
        if (xv[2]) {
            pr2a = *reinterpret_cast<const float4*>(x2 + b0off[2] + co);
            pr2b = *reinterpret_cast<const float4*>(x2 + b0off[2] + co + HW);
        }
    };
    auto WRITE = [&](int sel) {            // called with literal sel -> folds
        unsigned int* S1 = s1[sel];
        unsigned int* S2 = s2[sel];
        if (x1act) {
            S1[c1 + ((0 ^ X1) << 2)] = packh2(pr0a.x, pr0b.x);
            S1[c1 + ((1 ^ X1) << 2)] = packh2(pr0a.y, pr0b.y);
            S1[c1 + ((2 ^ X1) << 2)] = packh2(pr0a.z, pr0b.z);
            S1[c1 + ((3 ^ X1) << 2)] = packh2(pr0a.w, pr0b.w);
        } else if (xv[0]) {
            S2[c2[0] + ((0 ^ X2[0]) << 2)] = packh2(pr0a.x, pr0b.x);
            S2[c2[0] + ((1 ^ X2[0]) << 2)] = packh2(pr0a.y, pr0b.y);
            S2[c2[0] + ((2 ^ X2[0]) << 2)] = packh2(pr0a.z, pr0b.z);
            S2[c2[0] + ((3 ^ X2[0]) << 2)] = packh2(pr0a.w, pr0b.w);
        }
        if (xv[1]) {
            S2[c2[1] + ((0 ^ X2[1]) << 2)] = packh2(pr1a.x, pr1b.x);
            S2[c2[1] + ((1 ^ X2[1]) << 2)] = packh2(pr1a.y, pr1b.y);
            S2[c2[1] + ((2 ^ X2[1]) << 2)] = packh2(pr1a.z, pr1b.z);
            S2[c2[1] + ((3 ^ X2[1]) << 2)] = packh2(pr1a.w, pr1b.w);
        }
        if (xv[2]) {
            S2[c2[2] + ((0 ^ X2[2]) << 2)] = packh2(pr2a.x, pr2b.x);
            S2[c2[2] + ((1 ^ X2[2]) << 2)] = packh2(pr2a.y, pr2b.y);
            S2[c2[2] + ((2 ^ X2[2]) << 2)] = packh2(pr2a.z, pr2b.z);
            S2[c2[2] + ((3 ^ X2[2]) << 2)] = packh2(pr2a.w, pr2b.w);
        }
    };

    // ---------------- compute setup ----------------
    const int base1 = hr * 512 + (wq >> 1) * 32;
    const int S1X   = (4 * (wq & 1)) ^ ((wq >> 1) & 7) ^ hr;
    const int row   = hr + dy;            // 0..9
    const int row7  = row & 7;

    int a2[12];                           // chunk-invariant x2 read addresses
    #pragma unroll
    for (int t = 0; t < 12; ++t) {
        const int sp = 4 * wq + t;        // padded pixel index 0..135
        a2[t] = row * 544 + (sp >> 3) * 32
              + (((sp & 7) ^ ((sp >> 3) & 7) ^ row7) << 2);
    }

    float acc[4][9];
    #pragma unroll
    for (int p = 0; p < 4; ++p)
        #pragma unroll
        for (int d = 0; d < 9; ++d) acc[p][d] = 0.f;

    auto COMPUTE = [&](int sel) {         // called with literal sel -> folds
        const unsigned int* S1 = s1[sel];
        const unsigned int* S2 = s2[sel];
        uint4 x1v[4];
        #pragma unroll
        for (int p = 0; p < 4; ++p)
            x1v[p] = *reinterpret_cast<const uint4*>(&S1[base1 + ((p ^ S1X) << 2)]);
        #pragma unroll
        for (int t = 0; t < 12; ++t) {
            const uint4 x2v = *reinterpret_cast<const uint4*>(&S2[a2[t]]);
            #pragma unroll
            for (int p = 0; p < 4; ++p) {
                const int dxx = t - p;          // compile-time after unroll
                if (dxx >= 0 && dxx <= 8) {
                    float a = acc[p][dxx];
                    a = dot2(x1v[p].x, x2v.x, a);
                    a = dot2(x1v[p].y, x2v.y, a);
                    a = dot2(x1v[p].z, x2v.z, a);
                    a = dot2(x1v[p].w, x2v.w, a);
                    acc[p][dxx] = a;
                }
            }
        }
    };

    // ---------------- pipelined chunk loop (dbuf, 1 barrier/chunk) ---------
    // zero pad slots of both s2 buffers (never rewritten)
    for (int i = tid; i < 2 * S2SZ; i += 576) (&s2[0][0])[i] = 0u;
    LOAD(0);
    __syncthreads();                  // zeros visible before any WRITE
    WRITE(0);
    LOAD(1);
    __syncthreads();                  // buf0 ready

    #pragma unroll 1
    for (int cc = 0; cc < NCH; cc += 2) {
        COMPUTE(0);                   // chunk cc
        WRITE(1);                     // chunk cc+1 (loaded last section)
        if (cc + 2 < NCH) LOAD(cc + 2);
        __syncthreads();
        COMPUTE(1);                   // chunk cc+1
        if (cc + 2 < NCH) {
            WRITE(0);                 // chunk cc+2
            if (cc + 3 < NCH) LOAD(cc + 3);
        }
        __syncthreads();
    }

    // ---------------- epilogue: mean + leaky_relu + coalesced f32x4 writes -
    const float inv = 1.0f / 256.0f;
    float* ob = out + (((size_t)(b * 81 + dy * 9)) * H_ + (h0 + hr)) * W_ + wq * 4;
    #pragma unroll
    for (int dxx = 0; dxx < 9; ++dxx) {
        float4 o;
        float v;
        v = acc[0][dxx] * inv; o.x = v >= 0.f ? v : 0.1f * v;
        v = acc[1][dxx] * inv; o.y = v >= 0.f ? v : 0.1f * v;
        v = acc[2][dxx] * inv; o.z = v >= 0.f ? v : 0.1f * v;
        v = acc[3][dxx] * inv; o.w = v >= 0.f ? v : 0.1f * v;
        *reinterpret_cast<float4*>(ob + (size_t)dxx * HW) = o;
    }
}

extern "C" void kernel_launch(void* const* d_in, const int* in_sizes, int n_in,
                              void* d_out, int out_size, void* d_ws, size_t ws_size,
                              hipStream_t stream) {
    const float* x1 = (const float*)d_in[0];
    const float* x2 = (const float*)d_in[1];
    float* out = (float*)d_out;
    corr_kernel<<<dim3(B_ * (H_ / TH)), dim3(576), 0, stream>>>(x1, x2, out);
}

// Round 7
// 125.952 us; speedup vs baseline: 3.9149x; 3.8863x over previous
//
#include <hip/hip_runtime.h>

// PWC-Net correlation (md=4, 81 disps) + leaky_relu(0.1), mean over C=256.
// B=8 C=256 H=96 W=128, f32 in/out.
//
// R7: SMALL BLOCKS for co-residency. Evidence R2-R6: occupancy pinned at
// ~19.7% (= one 9-wave block/CU) regardless of grid; with no cross-block
// TLP, per-chunk global latency + barrier convoy exposed => ~190us floor.
// Now: block = 3 waves (192 thr), wave = one dy of a 3-dy group; grid =
// 8 (batch==XCD) x 48 (h-tiles) x 3 (dy-groups) = 1152 blocks = 4.5/CU.
// x2 staged rows 10 -> 4 per block (1.2x restage, L2-absorbed).
// Direct staging (load->pack->write, short live ranges; R3-proven to fit
// the compiler's fixed 84-VGPR budget -- R5/R6 lesson: attributes cannot
// raise it, spills cost 350us). Same conflict-free XOR swizzle + b128.

#define B_ 8
#define C_ 256
#define H_ 96
#define W_ 128
#define TH 2
#define CC 8
#define NCH (C_ / CC)            // 32 chunks
#define HW (H_ * W_)
#define CHSTRIDE (CC * HW)       // floats, fits u32
#define S2SZ (4 * 544)           // 2176 u32 (4 staged x2 rows)
#define S1SZ (TH * 512)          // 1024 u32
#define SMSZ (S2SZ + S1SZ)       // 3200 u32 = 12.8 KB
#define NTHR 192
#define NTASK 800                // 256 x1 + 544 x2 float4-pair tasks
#define NR 5                     // staging rounds: 192*5 >= 800

typedef __fp16 h2_t __attribute__((ext_vector_type(2)));
union H2U { unsigned int u; h2_t h; };

__device__ __forceinline__ h2_t u_as_h2(unsigned int u) { H2U x; x.u = u; return x.h; }

__device__ __forceinline__ unsigned int packh2(float a, float b) {
    H2U x; x.h = __builtin_amdgcn_cvt_pkrtz(a, b); return x.u;
}

#if __has_builtin(__builtin_amdgcn_fdot2)
__device__ __forceinline__ float dot2(unsigned int a, unsigned int b, float c) {
    return __builtin_amdgcn_fdot2(u_as_h2(a), u_as_h2(b), c, false);
}
#else
__device__ __forceinline__ float dot2(unsigned int a, unsigned int b, float c) {
    h2_t ha = u_as_h2(a), hb = u_as_h2(b);
    return c + (float)ha[0] * (float)hb[0] + (float)ha[1] * (float)hb[1];
}
#endif

__global__ __attribute__((amdgpu_flat_work_group_size(NTHR, NTHR)))
void corr_kernel(const float* __restrict__ x1, const float* __restrict__ x2,
                 float* __restrict__ out)
{
    // s2 (4 rows x 544) at [0, S2SZ), s1 (2 rows x 512) at [S2SZ, SMSZ)
    __shared__ __align__(16) unsigned int smem[SMSZ];

    const int b   = blockIdx.x;       // batch == XCD (x fastest => round-robin)
    const int h0  = blockIdx.y * TH;
    const int dg  = blockIdx.z;       // dy group: dy = 3*dg + wid
    const int tid = threadIdx.x;
    const int wid = tid >> 6;         // 0..2
    const int lane = tid & 63;
    const int hr  = lane >> 5;        // 0..1
    const int wq  = lane & 31;        // 32 groups of 4 w pixels

    // ---------------- staging descriptors (5 rounds x 192 threads) ---------
    // task u<256: x1. cp=u&3, w4=(u>>2)&31, rx=u>>7.
    // task 256<=u<800: x2. v=u-256: cp=v&3, q=v>>2, g=q%34 (0..33), r=q/34 (0..3).
    // LDS slot for pixel-slot s, ch-pair cp, row r:
    //   r*544(or 512) + (s>>3)*32 + (((s&7)^((s>>3)&7)^(r&7))<<2) + cp
    // task covers s=4g..4g+3 -> idx_k = c + ((k^X)<<2).
    unsigned off_[NR];
    int cx_[NR];                       // c | (X<<16)
    int mval = 0, msrc = 0;            // valid / source-is-x2 bitmasks
    #pragma unroll
    for (int r5 = 0; r5 < NR; ++r5) {
        const int u = tid + NTHR * r5;
        unsigned off = 0; int c = 0, X = 0; bool val = false, src2 = false;
        if (u < 256) {
            const int cp = u & 3, w4 = (u >> 2) & 31, rx = u >> 7;
            off = ((unsigned)(b * C_ + 2 * cp) * H_ + (unsigned)(h0 + rx)) * W_
                + (unsigned)(4 * w4);
            c = S2SZ + rx * 512 + (w4 >> 1) * 32 + cp;
            X = (4 * (w4 & 1)) ^ ((w4 >> 1) & 7) ^ rx;
            val = true;
        } else if (u < NTASK) {
            const int v = u - 256;
            const int cp = v & 3, q = v >> 2;
            const int g = q % 34, r = q / 34;
            const int h2 = h0 + 3 * dg + r - 4;
            val = (h2 >= 0) && (h2 < H_) && (g >= 1) && (g <= 32);
            const int h2c = val ? h2 : 0, gc = val ? g : 1;
            off = ((unsigned)(b * C_ + 2 * cp) * H_ + (unsigned)h2c) * W_
                + (unsigned)(4 * gc - 4);
            c = r * 544 + (g >> 1) * 32 + cp;
            X = (4 * (g & 1)) ^ ((g >> 1) & 7) ^ (r & 7);
            src2 = true;
        }
        off_[r5] = off;
        cx_[r5]  = c | (X << 16);
        mval |= (int)val << r5;
        msrc |= (int)src2 << r5;
    }

    // zero pad slots of s2 (g=0/33 and out-of-range rows; never rewritten)
    for (int i = tid; i < S2SZ; i += NTHR) smem[i] = 0u;
    __syncthreads();

    // ---------------- compute setup ----------------
    const int base1 = S2SZ + hr * 512 + (wq >> 1) * 32;
    const int S1X   = (4 * (wq & 1)) ^ ((wq >> 1) & 7) ^ hr;
    const int row   = hr + wid;            // staged x2 row 0..3

    int a2[12];                            // chunk-invariant x2 read addresses
    #pragma unroll
    for (int t = 0; t < 12; ++t) {
        const int sp = 4 * wq + t;         // padded pixel index 0..135
        a2[t] = row * 544 + (sp >> 3) * 32
              + (((sp & 7) ^ ((sp >> 3) & 7) ^ row) << 2);
    }

    float acc[4][9];
    #pragma unroll
    for (int p = 0; p < 4; ++p)
        #pragma unroll
        for (int d = 0; d < 9; ++d) acc[p][d] = 0.f;

    // ---------------- chunk loop: stage; sync; compute; sync ---------------
    #pragma unroll 1
    for (int cc = 0; cc < NCH; ++cc) {
        const unsigned co = (unsigned)cc * (unsigned)CHSTRIDE;
        #pragma unroll
        for (int r5 = 0; r5 < NR; ++r5) {
            if ((mval >> r5) & 1) {
                const float* base = ((msrc >> r5) & 1) ? x2 : x1;
                const float4 A = *reinterpret_cast<const float4*>(base + off_[r5] + co);
                const float4 Bv = *reinterpret_cast<const float4*>(base + off_[r5] + co + HW);
                const int c = cx_[r5] & 0xffff;
                const int X = cx_[r5] >> 16;
                smem[c + ((0 ^ X) << 2)] = packh2(A.x, Bv.x);
                smem[c + ((1 ^ X) << 2)] = packh2(A.y, Bv.y);
                smem[c + ((2 ^ X) << 2)] = packh2(A.z, Bv.z);
                smem[c + ((3 ^ X) << 2)] = packh2(A.w, Bv.w);
            }
        }
        __syncthreads();

        uint4 x1v[4];
        #pragma unroll
        for (int p = 0; p < 4; ++p)
            x1v[p] = *reinterpret_cast<const uint4*>(&smem[base1 + ((p ^ S1X) << 2)]);
        #pragma unroll
        for (int t = 0; t < 12; ++t) {
            const uint4 x2v = *reinterpret_cast<const uint4*>(&smem[a2[t]]);
            #pragma unroll
            for (int p = 0; p < 4; ++p) {
                const int dxx = t - p;          // compile-time after unroll
                if (dxx >= 0 && dxx <= 8) {
                    float a = acc[p][dxx];
                    a = dot2(x1v[p].x, x2v.x, a);
                    a = dot2(x1v[p].y, x2v.y, a);
                    a = dot2(x1v[p].z, x2v.z, a);
                    a = dot2(x1v[p].w, x2v.w, a);
                    acc[p][dxx] = a;
                }
            }
        }
        __syncthreads();
    }

    // ---------------- epilogue: mean + leaky_relu + coalesced f32x4 writes -
    const float inv = 1.0f / 256.0f;
    const int dy = 3 * dg + wid;
    float* ob = out + (((size_t)(b * 81 + dy * 9)) * H_ + (h0 + hr)) * W_ + wq * 4;
    #pragma unroll
    for (int dxx = 0; dxx < 9; ++dxx) {
        float4 o;
        float v;
        v = acc[0][dxx] * inv; o.x = v >= 0.f ? v : 0.1f * v;
        v = acc[1][dxx] * inv; o.y = v >= 0.f ? v : 0.1f * v;
        v = acc[2][dxx] * inv; o.z = v >= 0.f ? v : 0.1f * v;
        v = acc[3][dxx] * inv; o.w = v >= 0.f ? v : 0.1f * v;
        *reinterpret_cast<float4*>(ob + (size_t)dxx * HW) = o;
    }
}

extern "C" void kernel_launch(void* const* d_in, const int* in_sizes, int n_in,
                              void* d_out, int out_size, void* d_ws, size_t ws_size,
                              hipStream_t stream) {
    const float* x1 = (const float*)d_in[0];
    const float* x2 = (const float*)d_in[1];
    float* out = (float*)d_out;
    corr_kernel<<<dim3(B_, H_ / TH, 3), dim3(NTHR), 0, stream>>>(x1, x2, out);
}